// Round 3
// baseline (8318.468 us; speedup 1.0000x reference)
//
#include <hip/hip_runtime.h>
#include <math.h>

// Problem constants
#define B_    256
#define NPTS  1024
#define T_    50

// ---------------------------------------------------------------------------
// ws layout (bytes):
//   [0,       786432)   wp   f32 [64][3][256][4]  packed W_hh (round-7 layout)
//   [786432,  1310720)  henc u32 [256][512]       (f32-bit maxpool via atomicMax)
// ---------------------------------------------------------------------------

__global__ __launch_bounds__(256) void prep_kernel(
    const float* __restrict__ whh, float* __restrict__ wp,
    unsigned* __restrict__ henc) {
  int idx = blockIdx.x * 256 + threadIdx.x;   // grid 768*256 = 196608
  if (idx < 196608) {
    int c = idx & 3;
    int r = idx >> 2;            // (k4*3+j)*256 + t
    int t2 = r & 255;
    int q = r >> 8;              // k4*3 + j
    int j = q % 3;
    int k4 = q / 3;
    wp[idx] = whh[(j * 256 + t2) * 256 + (k4 * 4 + c)];
  }
  if (idx < 131072) henc[idx] = 0u;           // bits 0 == +0.0f; relu>=0 valid
}

// ---------------------------------------------------------------------------
// Encoder (byte-identical math to passing rounds 5-7): block = half sample,
// grid 512. Wave-uniform output slices -> weights via scalar s_loads.
// ---------------------------------------------------------------------------
__global__ __launch_bounds__(1024) void enc_kernel(
    const float* __restrict__ data,
    const float* __restrict__ w1, const float* __restrict__ b1,
    const float* __restrict__ w2, const float* __restrict__ b2,
    const float* __restrict__ w3, const float* __restrict__ b3,
    unsigned* __restrict__ henc) {
  __shared__ float h2t[128][66];
  const int t = threadIdx.x;
  const int b = blockIdx.x >> 1;
  const int half = blockIdx.x & 1;
  const int lane = t & 63;
  const int wv = __builtin_amdgcn_readfirstlane(t >> 6);   // wave id 0..15

  float m[32];
#pragma unroll
  for (int o = 0; o < 32; ++o) m[o] = 0.0f;                // relu via max w/ 0
  const float* __restrict__ w3b = w3 + wv * 32;

#pragma unroll 1
  for (int tile = 0; tile < 8; ++tile) {
    {
      const int ptg = b * NPTS + half * 512 + tile * 64 + lane;
      const float x0 = data[ptg * 3], x1 = data[ptg * 3 + 1], x2 = data[ptg * 3 + 2];
      float a[8];
#pragma unroll
      for (int c = 0; c < 8; ++c) a[c] = b2[wv * 8 + c];   // s_load
#pragma unroll 4
      for (int j = 0; j < 64; ++j) {                       // w1/b1 uniform
        float hj = fmaf(x0, w1[j], fmaf(x1, w1[64 + j], fmaf(x2, w1[128 + j], b1[j])));
        hj = fmaxf(hj, 0.0f);
        const float* __restrict__ w2r = w2 + j * 128 + wv * 8;  // s_load x8
#pragma unroll
        for (int c = 0; c < 8; ++c) a[c] = fmaf(hj, w2r[c], a[c]);
      }
#pragma unroll
      for (int c = 0; c < 8; ++c) h2t[wv * 8 + c][lane] = fmaxf(a[c], 0.0f);
    }
    __syncthreads();

    float acc[32];
#pragma unroll
    for (int o = 0; o < 32; ++o) acc[o] = b3[wv * 32 + o]; // s_load
#pragma unroll 4
    for (int k = 0; k < 128; ++k) {
      const float hk = h2t[k][lane];                       // ds_read_b32
      const float* __restrict__ wr = w3b + k * 512;        // uniform -> s_load
#pragma unroll
      for (int o = 0; o < 32; ++o) acc[o] = fmaf(hk, wr[o], acc[o]);
    }
#pragma unroll
    for (int o = 0; o < 32; ++o) m[o] = fmaxf(m[o], acc[o]);
    __syncthreads();                                       // h2t reuse guard
  }

#pragma unroll
  for (int off = 32; off > 0; off >>= 1) {
#pragma unroll
    for (int o = 0; o < 32; ++o) m[o] = fmaxf(m[o], __shfl_xor(m[o], off, 64));
  }
  if (lane == 0) {
    unsigned* __restrict__ hr = henc + b * 512 + wv * 32;
#pragma unroll
    for (int o = 0; o < 32; ++o) atomicMax(hr + o, __float_as_uint(m[o]));
  }
}

// ---------------------------------------------------------------------------
// Fast f64 exp (Cody-Waite + degree-13 Taylor, exact 1/k! coeffs, branch-
// free, ~1 ulp for |x| < 700). Perturbs vs libm at ~1e-16 rel -> invisible
// at f32 output rounding (f64-perturbation invariance proven rounds 4-7).
// ---------------------------------------------------------------------------
__device__ __forceinline__ double fexp(double x) {
  const double n = rint(x * 1.44269504088896338700e+00);
  const double r = fma(-n, 1.90821492927058770002e-10,
                       fma(-n, 6.93147180369123816490e-01, x));
  double p = 1.0 / 6227020800.0;                 // 1/13!
  p = fma(p, r, 1.0 / 479001600.0);
  p = fma(p, r, 1.0 / 39916800.0);
  p = fma(p, r, 1.0 / 3628800.0);
  p = fma(p, r, 1.0 / 362880.0);
  p = fma(p, r, 1.0 / 40320.0);
  p = fma(p, r, 1.0 / 5040.0);
  p = fma(p, r, 1.0 / 720.0);
  p = fma(p, r, 1.0 / 120.0);
  p = fma(p, r, 1.0 / 24.0);
  p = fma(p, r, 1.0 / 6.0);
  p = fma(p, r, 0.5);
  p = fma(p, r, 1.0);
  p = fma(p, r, 1.0);
  return ldexp(p, (int)n);
}
__device__ __forceinline__ double fsigm(double x) { return 1.0 / (1.0 + fexp(-x)); }
__device__ __forceinline__ double ftanh(double y) {
  const double e = fexp(-2.0 * y);
  return (1.0 - e) / (1.0 + e);
}

// ---------------------------------------------------------------------------
// GRU rollout, f64. Round-10: REGISTER-RESIDENT W_hh + all 256 CUs.
//   grid 256 (1 sample/block), block 640 (10 waves):
//   * waves 0-7 (t<512): matvec, thread = (c = t&255, k-half hh). Each thread
//     holds its 3x128 W_hh slice in 96 float4 = 384 VGPRs, loaded ONCE from
//     wp before the rollout; the 50-step loop has ZERO global loads (rounds
//     8/9 lost to hiding/spilling the 786KB/step wp stream; this removes it).
//   * gates on t<256 (single sample): comb = own half0 (bias-seeded) +
//     pp[half1]  -- bit-identical to round-0's per-sample association
//     (f64 a+b commutative).
//   * waves 8-9: out_mlp, round-0 3-stage split (L1 2-way k-split on 128
//     thr; combine+L2 on 64 thr wave-sync; L3+gia+stores on 6 thr), weights
//     f32-in-LDS, (double) convert on use (exact; proven round 9).
//   * matvec chunked 11/11/10 k4 across the 3 out_mlp phases (round-0
//     layout); barriers are cheap now -- no vmem in flight to drain.
//   __launch_bounds__(640,2): cap VGPR at 512, stop the occupancy heuristic
//   that spilled rounds 8/9 (84 VGPRs + scratch). All loops over weight
//   arrays fully unrolled -> static register indices only.
// ---------------------------------------------------------------------------
__global__ __launch_bounds__(640, 2) void gru_kernel(
    const float* __restrict__ henc,     // [256][512] (maxpool bits)
    const float* __restrict__ mw1, const float* __restrict__ mb1,
    const float* __restrict__ mw2, const float* __restrict__ mb2,
    const float* __restrict__ mw3, const float* __restrict__ mb3,
    const float* __restrict__ wih, const float* __restrict__ wp,
    const float* __restrict__ bih, const float* __restrict__ bhh,
    const float* __restrict__ ow1, const float* __restrict__ ob1,
    const float* __restrict__ ow2, const float* __restrict__ ob2,
    const float* __restrict__ ow3, const float* __restrict__ ob3,
    float* __restrict__ dout) {
  __shared__ __align__(16) double h_l[256];     // single sample
  __shared__ double pp[3][256];                 // half1 partials [gate][c]
  __shared__ __align__(16) float ow1f[16384];   // phase-0 alias: g1(256d)+g2(128d)
  __shared__ __align__(16) float ow2f[4096];
  __shared__ float ow3f[384];
  __shared__ float wihf[4608];
  __shared__ float bihf[768];
  __shared__ double o1p[2][64];                 // L1 k-split partials
  __shared__ double o1_l[64];
  __shared__ double o2_l[64];
  __shared__ double gia_l[6];

  const int t = threadIdx.x;
  const int s = blockIdx.x;                     // sample

  for (int i = t; i < 4608; i += 640) wihf[i] = wih[i];
  for (int i = t; i < 768; i += 640) bihf[i] = bih[i];

  double* const g1_l = (double*)ow1f;           // 256 doubles (phase 0 only)
  double* const g2_l = (double*)ow1f + 256;     // 128 doubles (phase 0 only)

  // ---- phase 0: gru_h init MLP (512->256->128->256), f64 (round-7 math) --
  if (t < 256) {
    const float* __restrict__ hrow = henc + (s << 9);
    double a = (double)mb1[t];
#pragma unroll 4
    for (int k = 0; k < 512; ++k)
      a = fma((double)hrow[k], (double)mw1[k * 256 + t], a);
    g1_l[t] = fmax(a, 0.0);
  }
  __syncthreads();
  if (t < 128) {
    double a = (double)mb2[t];
#pragma unroll 4
    for (int k = 0; k < 256; ++k) a = fma(g1_l[k], (double)mw2[k * 128 + t], a);
    g2_l[t] = fmax(a, 0.0);
  }
  __syncthreads();
  if (t < 256) {
    double a = (double)mb3[t];
#pragma unroll 4
    for (int k = 0; k < 128; ++k) a = fma(g2_l[k], (double)mw3[k * 256 + t], a);
    h_l[t] = a;
  }
  if (t < 6) gia_l[t] = 0.0;
  __syncthreads();                    // phase-0 reads of g1/g2 complete

  // ---- stage out_mlp f32 weights into LDS (overwrites g1/g2 region) ----
  for (int i = t; i < 16384; i += 640) ow1f[i] = ow1[i];
  for (int i = t; i < 4096; i += 640) ow2f[i] = ow2[i];
  if (t < 384) ow3f[t] = ow3[t];

  // ---- thread constants ----
  const int c = t & 255;
  const int hh = (t >> 8) & 1;                 // k-half (t<512)
  const int khome = hh << 5;                   // k4 range [khome, khome+32)
  const double br = (t < 512 && hh == 0) ? (double)bhh[c] : 0.0;
  const double bz = (t < 512 && hh == 0) ? (double)bhh[256 + c] : 0.0;
  const double bn = (t < 512 && hh == 0) ? (double)bhh[512 + c] : 0.0;
  double hreg = (t < 256) ? h_l[c] : 0.0;      // own phase-0 write

  // out_mlp constants (waves 8,9)
  const int tb = t - 512;
  const int ln = t & 63;
  double ob1d = 0.0, ob2d = 0.0, ob3d = 0.0;
  if (t >= 512) {
    ob1d = (double)ob1[ln];
    ob2d = (double)ob2[ln];
    if (ln < 6) ob3d = (double)ob3[ln];
  }

  // ---- register-resident W_hh slice: 96 float4 = 384 VGPRs ----
  float4 wr[32], wz[32], wn[32];
#pragma unroll
  for (int kk = 0; kk < 32; ++kk) {
    const float* p_ = wp + ((khome + kk) * 768 + c) * 4;
    wr[kk] = *(const float4*)(p_);
    wz[kk] = *(const float4*)(p_ + 1024);
    wn[kk] = *(const float4*)(p_ + 2048);
  }

  double ar, az, an;

  // FMA order per k4 identical to round-0's sample-0 chain:
  // ar: ha.x,ha.y,hb.x,hb.y then az x4 then an x4, k4 ascending.
#define MV_K(kk) {                                                           \
    const double2 ha = *(const double2*)(h_l + ((khome + (kk)) << 2));       \
    const double2 hb = *(const double2*)(h_l + ((khome + (kk)) << 2) + 2);   \
    ar = fma(ha.x, (double)wr[kk].x, ar); ar = fma(ha.y, (double)wr[kk].y, ar); \
    ar = fma(hb.x, (double)wr[kk].z, ar); ar = fma(hb.y, (double)wr[kk].w, ar); \
    az = fma(ha.x, (double)wz[kk].x, az); az = fma(ha.y, (double)wz[kk].y, az); \
    az = fma(hb.x, (double)wz[kk].z, az); az = fma(hb.y, (double)wz[kk].w, az); \
    an = fma(ha.x, (double)wn[kk].x, an); an = fma(ha.y, (double)wn[kk].y, an); \
    an = fma(hb.x, (double)wn[kk].z, an); an = fma(hb.y, (double)wn[kk].w, an); \
  }

  // ---- prologue: both halves' partials of comb(h0) ----
  if (t < 512) {
    ar = br; az = bz; an = bn;
#pragma unroll
    for (int kk = 0; kk < 32; ++kk) MV_K(kk)
    if (hh) { pp[0][c] = ar; pp[1][c] = az; pp[2][c] = an; }
  }
  __syncthreads();                    // pp + staged LDS weights visible

#pragma unroll 1
  for (int step = 0; step < T_; ++step) {
    // ---- gates (t<256): comb = own half0 (biased) + half1 from pp ----
    if (t < 256) {
      const double cr = ar + pp[0][c];
      const double cz = az + pp[1][c];
      const double cn = an + pp[2][c];
      double gr = (double)bihf[c], gz = (double)bihf[256 + c],
             gn = (double)bihf[512 + c];
#pragma unroll
      for (int a = 0; a < 6; ++a) {
        const double xa = gia_l[a];
        gr = fma((double)wihf[c * 6 + a], xa, gr);
        gz = fma((double)wihf[(256 + c) * 6 + a], xa, gz);
        gn = fma((double)wihf[(512 + c) * 6 + a], xa, gn);
      }
      const double rv = fsigm(cr + gr);
      const double zv = fsigm(cz + gz);
      const double nv = ftanh(fma(rv, cn, gn));
      hreg = fma(zv, hreg - nv, nv);
      h_l[c] = hreg;
    }
    if (t < 512) { ar = br; az = bz; an = bn; }
    __syncthreads();                  // [A] h published

    // ---- c1: matvec kk [0,11) || out_mlp L1 (2-way k-split, 128 thr) ----
    if (t < 512) {
#pragma unroll
      for (int kk = 0; kk < 11; ++kk) MV_K(kk)
    } else if (tb < 128) {
      const int q = tb >> 6, j = tb & 63;
      double a = (q == 0) ? ob1d : 0.0;
      const int k0 = q << 7;
#pragma unroll 4
      for (int k = k0; k < k0 + 128; ++k)
        a = fma(h_l[k], (double)ow1f[k * 64 + j], a);
      o1p[q][j] = a;
    }
    __syncthreads();

    // ---- c2: matvec kk [11,22) || combine o1 + L2 (wave-synchronous) ----
    if (t < 512) {
#pragma unroll
      for (int kk = 11; kk < 22; ++kk) MV_K(kk)
    } else if (tb < 64) {
      const int j = tb;
      o1_l[j] = fmax(o1p[0][j] + o1p[1][j], 0.0);
      __builtin_amdgcn_wave_barrier();                    // own-wave LDS only
      double b0 = ob2d;
#pragma unroll 4
      for (int k = 0; k < 64; ++k)
        b0 = fma(o1_l[k], (double)ow2f[k * 64 + j], b0);
      o2_l[j] = fmax(b0, 0.0);
    }
    __syncthreads();

    // ---- c3: matvec kk [22,32) + publish || L3 + gia + stores ----
    if (t < 512) {
#pragma unroll
      for (int kk = 22; kk < 32; ++kk) MV_K(kk)
      if (hh) { pp[0][c] = ar; pp[1][c] = az; pp[2][c] = an; }
    } else if (tb < 6) {
      double a = ob3d;
#pragma unroll 4
      for (int k = 0; k < 64; ++k) a = fma(o2_l[k], (double)ow3f[k * 6 + tb], a);
      const double gi_new = gia_l[tb] + a;
      gia_l[tb] = gi_new;
      dout[s * 300 + step * 6 + tb] = (float)a;              // dws
      dout[76800 + s * 300 + step * 6 + tb] = (float)gi_new; // ws
    }
    __syncthreads();                  // [B] pp + gia ready for next gates
  }
#undef MV_K
}

extern "C" void kernel_launch(void* const* d_in, const int* in_sizes, int n_in,
                              void* d_out, int out_size, void* d_ws, size_t ws_size,
                              hipStream_t stream) {
  const float* data = (const float*)d_in[0];
  // d_in[1] = horizon (always 50)
  const float* ew1 = (const float*)d_in[2];
  const float* eb1 = (const float*)d_in[3];
  const float* ew2 = (const float*)d_in[4];
  const float* eb2 = (const float*)d_in[5];
  const float* ew3 = (const float*)d_in[6];
  const float* eb3 = (const float*)d_in[7];
  const float* mw1 = (const float*)d_in[8];
  const float* mb1 = (const float*)d_in[9];
  const float* mw2 = (const float*)d_in[10];
  const float* mb2 = (const float*)d_in[11];
  const float* mw3 = (const float*)d_in[12];
  const float* mb3 = (const float*)d_in[13];
  const float* wih = (const float*)d_in[14];
  const float* whh = (const float*)d_in[15];
  const float* bih = (const float*)d_in[16];
  const float* bhh = (const float*)d_in[17];
  const float* ow1 = (const float*)d_in[18];
  const float* ob1 = (const float*)d_in[19];
  const float* ow2 = (const float*)d_in[20];
  const float* ob2 = (const float*)d_in[21];
  const float* ow3 = (const float*)d_in[22];
  const float* ob3 = (const float*)d_in[23];
  float* out = (float*)d_out;

  char* ws = (char*)d_ws;
  float*    wp   = (float*)(ws);                 // 786432 B
  unsigned* henc = (unsigned*)(ws + 786432);     // 524288 B -> end 1310720

  prep_kernel<<<768, 256, 0, stream>>>(whh, wp, henc);
  enc_kernel<<<512, 1024, 0, stream>>>(data, ew1, eb1, ew2, eb2, ew3, eb3, henc);
  gru_kernel<<<256, 640, 0, stream>>>((const float*)henc,
                                      mw1, mb1, mw2, mb2, mw3, mb3,
                                      wih, wp, bih, bhh,
                                      ow1, ob1, ow2, ob2, ow3, ob3,
                                      out);
}

// Round 4
// 1196.052 us; speedup vs baseline: 6.9549x; 6.9549x over previous
//
#include <hip/hip_runtime.h>
#include <math.h>

// Problem constants
#define B_    256
#define NPTS  1024
#define T_    50

// ---------------------------------------------------------------------------
// ws layout (bytes):
//   [0,       786432)   wp   f32 [64][3][256][4]  packed W_hh (round-7 layout)
//   [786432,  1310720)  henc u32 [256][512]       (f32-bit maxpool via atomicMax)
// ---------------------------------------------------------------------------

__global__ __launch_bounds__(256) void prep_kernel(
    const float* __restrict__ whh, float* __restrict__ wp,
    unsigned* __restrict__ henc) {
  int idx = blockIdx.x * 256 + threadIdx.x;   // grid 768*256 = 196608
  if (idx < 196608) {
    int c = idx & 3;
    int r = idx >> 2;            // (k4*3+j)*256 + t
    int t2 = r & 255;
    int q = r >> 8;              // k4*3 + j
    int j = q % 3;
    int k4 = q / 3;
    wp[idx] = whh[(j * 256 + t2) * 256 + (k4 * 4 + c)];
  }
  if (idx < 131072) henc[idx] = 0u;           // bits 0 == +0.0f; relu>=0 valid
}

// ---------------------------------------------------------------------------
// Encoder (byte-identical math to passing rounds 5-7): block = half sample,
// grid 512. Wave-uniform output slices -> weights via scalar s_loads.
// ---------------------------------------------------------------------------
__global__ __launch_bounds__(1024) void enc_kernel(
    const float* __restrict__ data,
    const float* __restrict__ w1, const float* __restrict__ b1,
    const float* __restrict__ w2, const float* __restrict__ b2,
    const float* __restrict__ w3, const float* __restrict__ b3,
    unsigned* __restrict__ henc) {
  __shared__ float h2t[128][66];
  const int t = threadIdx.x;
  const int b = blockIdx.x >> 1;
  const int half = blockIdx.x & 1;
  const int lane = t & 63;
  const int wv = __builtin_amdgcn_readfirstlane(t >> 6);   // wave id 0..15

  float m[32];
#pragma unroll
  for (int o = 0; o < 32; ++o) m[o] = 0.0f;                // relu via max w/ 0
  const float* __restrict__ w3b = w3 + wv * 32;

#pragma unroll 1
  for (int tile = 0; tile < 8; ++tile) {
    {
      const int ptg = b * NPTS + half * 512 + tile * 64 + lane;
      const float x0 = data[ptg * 3], x1 = data[ptg * 3 + 1], x2 = data[ptg * 3 + 2];
      float a[8];
#pragma unroll
      for (int c = 0; c < 8; ++c) a[c] = b2[wv * 8 + c];   // s_load
#pragma unroll 4
      for (int j = 0; j < 64; ++j) {                       // w1/b1 uniform
        float hj = fmaf(x0, w1[j], fmaf(x1, w1[64 + j], fmaf(x2, w1[128 + j], b1[j])));
        hj = fmaxf(hj, 0.0f);
        const float* __restrict__ w2r = w2 + j * 128 + wv * 8;  // s_load x8
#pragma unroll
        for (int c = 0; c < 8; ++c) a[c] = fmaf(hj, w2r[c], a[c]);
      }
#pragma unroll
      for (int c = 0; c < 8; ++c) h2t[wv * 8 + c][lane] = fmaxf(a[c], 0.0f);
    }
    __syncthreads();

    float acc[32];
#pragma unroll
    for (int o = 0; o < 32; ++o) acc[o] = b3[wv * 32 + o]; // s_load
#pragma unroll 4
    for (int k = 0; k < 128; ++k) {
      const float hk = h2t[k][lane];                       // ds_read_b32
      const float* __restrict__ wr = w3b + k * 512;        // uniform -> s_load
#pragma unroll
      for (int o = 0; o < 32; ++o) acc[o] = fmaf(hk, wr[o], acc[o]);
    }
#pragma unroll
    for (int o = 0; o < 32; ++o) m[o] = fmaxf(m[o], acc[o]);
    __syncthreads();                                       // h2t reuse guard
  }

#pragma unroll
  for (int off = 32; off > 0; off >>= 1) {
#pragma unroll
    for (int o = 0; o < 32; ++o) m[o] = fmaxf(m[o], __shfl_xor(m[o], off, 64));
  }
  if (lane == 0) {
    unsigned* __restrict__ hr = henc + b * 512 + wv * 32;
#pragma unroll
    for (int o = 0; o < 32; ++o) atomicMax(hr + o, __float_as_uint(m[o]));
  }
}

// ---------------------------------------------------------------------------
// Fast f64 exp (Cody-Waite + degree-13 Taylor, exact 1/k! coeffs, branch-
// free, ~1 ulp for |x| < 700). Perturbs vs libm at ~1e-16 rel -> invisible
// at f32 output rounding (f64-perturbation invariance proven rounds 4-7).
// ---------------------------------------------------------------------------
__device__ __forceinline__ double fexp(double x) {
  const double n = rint(x * 1.44269504088896338700e+00);
  const double r = fma(-n, 1.90821492927058770002e-10,
                       fma(-n, 6.93147180369123816490e-01, x));
  double p = 1.0 / 6227020800.0;                 // 1/13!
  p = fma(p, r, 1.0 / 479001600.0);
  p = fma(p, r, 1.0 / 39916800.0);
  p = fma(p, r, 1.0 / 3628800.0);
  p = fma(p, r, 1.0 / 362880.0);
  p = fma(p, r, 1.0 / 40320.0);
  p = fma(p, r, 1.0 / 5040.0);
  p = fma(p, r, 1.0 / 720.0);
  p = fma(p, r, 1.0 / 120.0);
  p = fma(p, r, 1.0 / 24.0);
  p = fma(p, r, 1.0 / 6.0);
  p = fma(p, r, 0.5);
  p = fma(p, r, 1.0);
  p = fma(p, r, 1.0);
  return ldexp(p, (int)n);
}
__device__ __forceinline__ double fsigm(double x) { return 1.0 / (1.0 + fexp(-x)); }
__device__ __forceinline__ double ftanh(double y) {
  const double e = fexp(-2.0 * y);
  return (1.0 - e) / (1.0 + e);
}

// ---------------------------------------------------------------------------
// GRU rollout, f64. Round-11: grid 256 (1 sample/block, ALL 256 CUs),
// block 576 (9 waves), 2 barriers/step, NO hand pipelining, NO register-
// resident weights (round-3 post-mortem: W_hh 786KB > 512KB CU regfile --
// impossible; rounds 1/2 spilled from hand-pipeline register pressure).
//   * waves 0-7 (t<512): matvec, thread = (c = t&255, k-half hh). One plain
//     32-k4 pass per step (round-0's proven unroll-2 JIT-load pattern; the
//     compiler schedules loads ahead within its VGPR budget -- round-0 ran
//     this spill-free at 64 VGPRs).
//   * gates on t<256: comb = own half0 (bias-seeded) + pp[half1] --
//     bit-identical association to round-0's per-sample chain.
//   * wave 8 (t in [512,576)): whole out_mlp, wave-private (round-2 proven):
//     L1 = (ob1 + asc k<128) + (asc k>=128), L2/L3 ascending; weights
//     f32-in-LDS, (double) convert on use (exact, round-2 proven); internal
//     wave_barrier only.
//   Per-CU wp stream stays 786KB/step (invariant; L1-return floor ~5.1us)
//   but per-thread VALU drops 36->24 ops/k4 and all 256 CUs now work.
// ---------------------------------------------------------------------------
__global__ __launch_bounds__(576) void gru_kernel(
    const float* __restrict__ henc,     // [256][512] (maxpool bits)
    const float* __restrict__ mw1, const float* __restrict__ mb1,
    const float* __restrict__ mw2, const float* __restrict__ mb2,
    const float* __restrict__ mw3, const float* __restrict__ mb3,
    const float* __restrict__ wih, const float* __restrict__ wp,
    const float* __restrict__ bih, const float* __restrict__ bhh,
    const float* __restrict__ ow1, const float* __restrict__ ob1,
    const float* __restrict__ ow2, const float* __restrict__ ob2,
    const float* __restrict__ ow3, const float* __restrict__ ob3,
    float* __restrict__ dout) {
  __shared__ __align__(16) double h_l[256];     // single sample
  __shared__ double pp[3][256];                 // half1 partials [gate][c]
  __shared__ __align__(16) float ow1f[16384];   // phase-0 alias: g1(256d)+g2(128d)
  __shared__ __align__(16) float ow2f[4096];
  __shared__ float ow3f[384];
  __shared__ float wihf[4608];
  __shared__ float bihf[768];
  __shared__ double o1_l[64];
  __shared__ double o2_l[64];
  __shared__ double gia_l[6];

  const int t = threadIdx.x;
  const int s = blockIdx.x;                     // sample

  for (int i = t; i < 4608; i += 576) wihf[i] = wih[i];
  for (int i = t; i < 768; i += 576) bihf[i] = bih[i];

  double* const g1_l = (double*)ow1f;           // 256 doubles (phase 0 only)
  double* const g2_l = (double*)ow1f + 256;     // 128 doubles (phase 0 only)

  // ---- phase 0: gru_h init MLP (512->256->128->256), f64 (round-7 math) --
  if (t < 256) {
    const float* __restrict__ hrow = henc + (s << 9);
    double a = (double)mb1[t];
#pragma unroll 4
    for (int k = 0; k < 512; ++k)
      a = fma((double)hrow[k], (double)mw1[k * 256 + t], a);
    g1_l[t] = fmax(a, 0.0);
  }
  __syncthreads();
  if (t < 128) {
    double a = (double)mb2[t];
#pragma unroll 4
    for (int k = 0; k < 256; ++k) a = fma(g1_l[k], (double)mw2[k * 128 + t], a);
    g2_l[t] = fmax(a, 0.0);
  }
  __syncthreads();
  if (t < 256) {
    double a = (double)mb3[t];
#pragma unroll 4
    for (int k = 0; k < 128; ++k) a = fma(g2_l[k], (double)mw3[k * 256 + t], a);
    h_l[t] = a;
  }
  if (t < 6) gia_l[t] = 0.0;
  __syncthreads();                    // phase-0 reads of g1/g2 complete

  // ---- stage out_mlp f32 weights into LDS (overwrites g1/g2 region) ----
  for (int i = t; i < 16384; i += 576) ow1f[i] = ow1[i];
  for (int i = t; i < 4096; i += 576) ow2f[i] = ow2[i];
  if (t < 384) ow3f[t] = ow3[t];
  // (visible to wave 8 after the post-prologue __syncthreads)

  // ---- thread constants ----
  const int c = t & 255;
  const int hh = (t >> 8) & 1;                 // k-half (t<512)
  const int khome = hh << 5;                   // k4 range [khome, khome+32)
  const double br = (t < 512 && hh == 0) ? (double)bhh[c] : 0.0;
  const double bz = (t < 512 && hh == 0) ? (double)bhh[256 + c] : 0.0;
  const double bn = (t < 512 && hh == 0) ? (double)bhh[512 + c] : 0.0;
  double hreg = (t < 256) ? h_l[c] : 0.0;      // own phase-0 write
  const float* const wpc = wp + c * 4;

  // out_mlp constants (wave 8)
  const int ln = t & 63;
  double ob1d = 0.0, ob2d = 0.0, ob3d = 0.0;
  if (t >= 512) {
    ob1d = (double)ob1[ln];
    ob2d = (double)ob2[ln];
    if (ln < 6) ob3d = (double)ob3[ln];
  }

  double ar, az, an;

  // FMA order per k4 identical to round-0's per-sample chain:
  // ar: ha.x,ha.y,hb.x,hb.y then az x4 then an x4, k4 ascending.
#define MV_K(kk) {                                                           \
    const float* p_ = wpc + (khome + (kk)) * 3072;                           \
    const float4 wr = *(const float4*)(p_);                                  \
    const float4 wz = *(const float4*)(p_ + 1024);                           \
    const float4 wn = *(const float4*)(p_ + 2048);                           \
    const double2 ha = *(const double2*)(h_l + ((khome + (kk)) << 2));       \
    const double2 hb = *(const double2*)(h_l + ((khome + (kk)) << 2) + 2);   \
    ar = fma(ha.x, (double)wr.x, ar); ar = fma(ha.y, (double)wr.y, ar);      \
    ar = fma(hb.x, (double)wr.z, ar); ar = fma(hb.y, (double)wr.w, ar);      \
    az = fma(ha.x, (double)wz.x, az); az = fma(ha.y, (double)wz.y, az);      \
    az = fma(hb.x, (double)wz.z, az); az = fma(hb.y, (double)wz.w, az);      \
    an = fma(ha.x, (double)wn.x, an); an = fma(ha.y, (double)wn.y, an);      \
    an = fma(hb.x, (double)wn.z, an); an = fma(hb.y, (double)wn.w, an);      \
  }

  // ---- prologue: both halves' partials of comb(h0) ----
  if (t < 512) {
    ar = br; az = bz; an = bn;
#pragma unroll 2
    for (int kk = 0; kk < 32; ++kk) MV_K(kk)
    if (hh) { pp[0][c] = ar; pp[1][c] = az; pp[2][c] = an; }
  }
  __syncthreads();                    // pp + staged LDS weights visible

#pragma unroll 1
  for (int step = 0; step < T_; ++step) {
    // ---- gates (t<256): comb = own half0 (biased) + half1 from pp ----
    if (t < 256) {
      const double cr = ar + pp[0][c];
      const double cz = az + pp[1][c];
      const double cn = an + pp[2][c];
      double gr = (double)bihf[c], gz = (double)bihf[256 + c],
             gn = (double)bihf[512 + c];
#pragma unroll
      for (int a = 0; a < 6; ++a) {
        const double xa = gia_l[a];
        gr = fma((double)wihf[c * 6 + a], xa, gr);
        gz = fma((double)wihf[(256 + c) * 6 + a], xa, gz);
        gn = fma((double)wihf[(512 + c) * 6 + a], xa, gn);
      }
      const double rv = fsigm(cr + gr);
      const double zv = fsigm(cz + gz);
      const double nv = ftanh(fma(rv, cn, gn));
      hreg = fma(zv, hreg - nv, nv);
      h_l[c] = hreg;
    }
    if (t < 512) { ar = br; az = bz; an = bn; }
    __syncthreads();                  // [A] h published

    if (t < 512) {
      // ---- matvec: one plain 32-k4 pass (compiler-scheduled loads) ----
#pragma unroll 2
      for (int kk = 0; kk < 32; ++kk) MV_K(kk)
      if (hh) { pp[0][c] = ar; pp[1][c] = az; pp[2][c] = an; }
    } else {
      // ---- out_mlp, wave-private (wave 8) ----
      double a0 = ob1d, a1 = 0.0;     // (ob1 + asc lo) + (asc hi): proven assoc
#pragma unroll 4
      for (int k = 0; k < 128; ++k) {
        a0 = fma(h_l[k], (double)ow1f[k * 64 + ln], a0);
        a1 = fma(h_l[128 + k], (double)ow1f[(128 + k) * 64 + ln], a1);
      }
      o1_l[ln] = fmax(a0 + a1, 0.0);
      __builtin_amdgcn_wave_barrier();                    // own-wave LDS only
      double b0 = ob2d;
#pragma unroll 4
      for (int k = 0; k < 64; ++k)
        b0 = fma(o1_l[k], (double)ow2f[k * 64 + ln], b0);
      o2_l[ln] = fmax(b0, 0.0);
      __builtin_amdgcn_wave_barrier();
      if (ln < 6) {
        double a = ob3d;
#pragma unroll 4
        for (int k = 0; k < 64; ++k)
          a = fma(o2_l[k], (double)ow3f[k * 6 + ln], a);
        const double gi_new = gia_l[ln] + a;
        gia_l[ln] = gi_new;
        dout[s * 300 + step * 6 + ln] = (float)a;              // dws
        dout[76800 + s * 300 + step * 6 + ln] = (float)gi_new; // ws
      }
    }
    __syncthreads();                  // [B] pp + gia ready for next gates
  }
#undef MV_K
}

extern "C" void kernel_launch(void* const* d_in, const int* in_sizes, int n_in,
                              void* d_out, int out_size, void* d_ws, size_t ws_size,
                              hipStream_t stream) {
  const float* data = (const float*)d_in[0];
  // d_in[1] = horizon (always 50)
  const float* ew1 = (const float*)d_in[2];
  const float* eb1 = (const float*)d_in[3];
  const float* ew2 = (const float*)d_in[4];
  const float* eb2 = (const float*)d_in[5];
  const float* ew3 = (const float*)d_in[6];
  const float* eb3 = (const float*)d_in[7];
  const float* mw1 = (const float*)d_in[8];
  const float* mb1 = (const float*)d_in[9];
  const float* mw2 = (const float*)d_in[10];
  const float* mb2 = (const float*)d_in[11];
  const float* mw3 = (const float*)d_in[12];
  const float* mb3 = (const float*)d_in[13];
  const float* wih = (const float*)d_in[14];
  const float* whh = (const float*)d_in[15];
  const float* bih = (const float*)d_in[16];
  const float* bhh = (const float*)d_in[17];
  const float* ow1 = (const float*)d_in[18];
  const float* ob1 = (const float*)d_in[19];
  const float* ow2 = (const float*)d_in[20];
  const float* ob2 = (const float*)d_in[21];
  const float* ow3 = (const float*)d_in[22];
  const float* ob3 = (const float*)d_in[23];
  float* out = (float*)d_out;

  char* ws = (char*)d_ws;
  float*    wp   = (float*)(ws);                 // 786432 B
  unsigned* henc = (unsigned*)(ws + 786432);     // 524288 B -> end 1310720

  prep_kernel<<<768, 256, 0, stream>>>(whh, wp, henc);
  enc_kernel<<<512, 1024, 0, stream>>>(data, ew1, eb1, ew2, eb2, ew3, eb3, henc);
  gru_kernel<<<256, 576, 0, stream>>>((const float*)henc,
                                      mw1, mb1, mw2, mb2, mw3, mb3,
                                      wih, wp, bih, bhh,
                                      ow1, ob1, ow2, ob2, ow3, ob3,
                                      out);
}